// Round 10
// baseline (415.927 us; speedup 1.0000x reference)
//
#include <hip/hip_runtime.h>
#include <hip/hip_bf16.h>

#define S_ 128
#define N_ 384
#define CM 256
#define CH 32
#define CZ 128

typedef __attribute__((ext_vector_type(8))) __bf16 bf16x8;
typedef __attribute__((ext_vector_type(4))) float f32x4;

union pack4 { __hip_bfloat16 h[4]; uint2 u; };

// ---- Kernel P: fused prep (wt12 + woutT + RN) — one launch ---------------
// blocks 0..63    : wt12[64][256] bf16 = [w1|w2]^T     (t < 256 active)
// blocks 64..191  : woutT[z][cd] bf16
// blocks 192..575 : RN[i][j] = 1/(mask^T mask + eps)   (384 thr = j)
__global__ __launch_bounds__(384) void k_prep(const float* __restrict__ w1,
                                              const float* __restrict__ w2,
                                              const float* __restrict__ wout,
                                              const float* __restrict__ mask,
                                              __hip_bfloat16* __restrict__ wt12,
                                              __hip_bfloat16* __restrict__ woutT,
                                              float* __restrict__ RN)
{
    const int b = blockIdx.x, t = threadIdx.x;
    if (b < 64) {
        if (t < 256) {
            const float* w = (b < CH) ? w1 : w2;
            wt12[b * CM + t] = __float2bfloat16(w[(size_t)t * CH + (b & 31)]);
        }
    } else if (b < 192) {
        const int z = b - 64;
        for (int cd = t; cd < CH*CH; cd += 384)
            woutT[(size_t)z * (CH*CH) + cd] = __float2bfloat16(wout[(size_t)cd * CZ + z]);
    } else {
        const int i = b - 192, j = t;
        float acc = 0.f;
        #pragma unroll 8
        for (int s = 0; s < S_; ++s)
            acc += mask[s*N_ + i] * mask[s*N_ + j];
        RN[i*N_ + j] = 1.0f / (acc + 1e-3f);
    }
}

// ---- Kernel 1: LayerNorm + dual projection via MFMA (unchanged) ----------
#define LNR 264
__global__ __launch_bounds__(256) void k_lnp(
    const float* __restrict__ m, const float* __restrict__ mask,
    const float* __restrict__ gamma, const float* __restrict__ beta,
    const float* __restrict__ b1, const float* __restrict__ b2,
    const __hip_bfloat16* __restrict__ wt12,
    __hip_bfloat16* __restrict__ At, __hip_bfloat16* __restrict__ Bt)
{
    __shared__ __hip_bfloat16 lnS[128 * LNR];
    __shared__ float msk[128];
    const int n0 = blockIdx.x * 16, s0 = blockIdx.y * 8;
    const int t = threadIdx.x, wave = t >> 6, lane = t & 63;
    const int l15 = lane & 15, quad = lane >> 4;

    if (t < 128) msk[t] = mask[(s0 + (t & 7))*N_ + n0 + (t >> 3)];

    float4 g  = ((const float4*)gamma)[lane];
    float4 be = ((const float4*)beta)[lane];
    for (int i = 0; i < 32; ++i) {
        const int row = wave*32 + i;
        const int n = row >> 3, s = row & 7;
        float4 x = ((const float4*)(m + ((size_t)((s0+s)*N_ + n0 + n)) * CM))[lane];
        float sum = x.x + x.y + x.z + x.w;
        float ssq = x.x*x.x + x.y*x.y + x.z*x.z + x.w*x.w;
        #pragma unroll
        for (int off = 32; off >= 1; off >>= 1) {
            sum += __shfl_xor(sum, off, 64);
            ssq += __shfl_xor(ssq, off, 64);
        }
        const float mean = sum * (1.0f/CM);
        const float var  = ssq * (1.0f/CM) - mean*mean;
        const float rstd = rsqrtf(var + 1e-5f);
        pack4 pk;
        pk.h[0] = __float2bfloat16((x.x - mean)*rstd*g.x + be.x);
        pk.h[1] = __float2bfloat16((x.y - mean)*rstd*g.y + be.y);
        pk.h[2] = __float2bfloat16((x.z - mean)*rstd*g.z + be.z);
        pk.h[3] = __float2bfloat16((x.w - mean)*rstd*g.w + be.w);
        *(uint2*)&lnS[row*LNR + lane*4] = pk.u;
    }
    __syncthreads();

    f32x4 acc[2][4];
    const f32x4 z4 = {0.f,0.f,0.f,0.f};
    #pragma unroll
    for (int mt = 0; mt < 2; ++mt)
        #pragma unroll
        for (int nt = 0; nt < 4; ++nt) acc[mt][nt] = z4;

    #pragma unroll
    for (int kk = 0; kk < 8; ++kk) {
        bf16x8 a0 = *(const bf16x8*)&lnS[(wave*32      + l15)*LNR + kk*32 + quad*8];
        bf16x8 a1 = *(const bf16x8*)&lnS[(wave*32 + 16 + l15)*LNR + kk*32 + quad*8];
        #pragma unroll
        for (int nt = 0; nt < 4; ++nt) {
            bf16x8 wv = *(const bf16x8*)&wt12[(size_t)(nt*16 + l15)*CM + kk*32 + quad*8];
            acc[0][nt] = __builtin_amdgcn_mfma_f32_16x16x32_bf16(a0, wv, acc[0][nt], 0,0,0);
            acc[1][nt] = __builtin_amdgcn_mfma_f32_16x16x32_bf16(a1, wv, acc[1][nt], 0,0,0);
        }
    }

    #pragma unroll
    for (int nt = 0; nt < 4; ++nt) {
        const int ncol = nt*16 + l15;
        const int sel = ncol >> 5, c = ncol & 31;
        const float bias = sel ? b2[c] : b1[c];
        __hip_bfloat16* dst = sel ? Bt : At;
        #pragma unroll
        for (int mt = 0; mt < 2; ++mt) {
            const int rowb = wave*32 + mt*16 + quad*4;
            const int n_loc = rowb >> 3, s_loc = rowb & 7;
            pack4 pk;
            #pragma unroll
            for (int r = 0; r < 4; ++r)
                pk.h[r] = __float2bfloat16((acc[mt][nt][r] + bias) * msk[rowb + r]);
            *(uint2*)&dst[((size_t)(n0 + n_loc)*CH + c)*S_ + s0 + s_loc] = pk.u;
        }
    }
}

// ---- Kernel 2: fused MFMA outer-product + w_out GEMM ---------------------
// R8 structure (8x8 pairs, 145 KB O, grid 48x48, 1024 thr / 16 waves =
// 4 waves/SIMD) with R8's measured spill fixed. R8 lesson: a 1024-thr
// block hard-caps TOTAL regs (arch+AGPR) at 128/thread (512-reg SIMD pool
// / 4 waves); the compiler picked 64 arch + 64 acc and spilled 24 MB
// because stage-3's wf[16] chunk alone needs 64 arch regs. Fixes:
//   1) __launch_bounds__(1024, 4): tell the allocator the real occupancy
//      target (4 waves/EU -> 128 total) instead of its 8-waves/EU default.
//   2) wf in FOUR chunks of 8 (32 arch regs): stage-3 arch live ~52,
//      stage-2 arch live ~60 -> both phases fit 64 arch + 64 AGPR.
// Spill tripwire: WRITE_SIZE must be ~74 MB (R8: 97.9 = spill).
#define OR 1160
__global__ __launch_bounds__(1024, 4) void k_opm(
    const __hip_bfloat16* __restrict__ At, const __hip_bfloat16* __restrict__ Bt,
    const float* __restrict__ RN, const __hip_bfloat16* __restrict__ woutT,
    const float* __restrict__ bout, float* __restrict__ out)
{
    __shared__ __hip_bfloat16 O[64 * OR];   // 145 KB
    const int t = threadIdx.x;
    const int wave = t >> 6, lane = t & 63;
    const int l15 = lane & 15, quad = lane >> 4;
    const int i0 = blockIdx.x * 8, j0 = blockIdx.y * 8;
    const int mq = wave & 3, nq = wave >> 2;     // 4x4 wave grid

    // ---- stage 2: acc[nt][mt] = D[(j,d)][(i,c)], wave = 64M x 64N ----
    f32x4 acc[4][4];
    const f32x4 z4 = {0.f,0.f,0.f,0.f};
    #pragma unroll
    for (int nt = 0; nt < 4; ++nt)
        #pragma unroll
        for (int mt = 0; mt < 4; ++mt) acc[nt][mt] = z4;

    const __hip_bfloat16* Ag[4];
    #pragma unroll
    for (int mt = 0; mt < 4; ++mt) {
        const int Mrow = mq*64 + mt*16 + l15;     // = i_l*32 + c
        Ag[mt] = At + ((size_t)(i0 + (Mrow >> 5)) * CH + (Mrow & 31)) * S_ + quad*8;
    }
    const __hip_bfloat16* Bg[4];
    #pragma unroll
    for (int nt = 0; nt < 4; ++nt) {
        const int Ncol = nq*64 + nt*16 + l15;     // = j_l*32 + d
        Bg[nt] = Bt + ((size_t)(j0 + (Ncol >> 5)) * CH + (Ncol & 31)) * S_ + quad*8;
    }

    #pragma unroll
    for (int kk = 0; kk < 4; ++kk) {
        bf16x8 af[4], bfr[4];
        #pragma unroll
        for (int mt = 0; mt < 4; ++mt) af[mt] = *(const bf16x8*)(Ag[mt] + kk*32);
        #pragma unroll
        for (int nt = 0; nt < 4; ++nt) bfr[nt] = *(const bf16x8*)(Bg[nt] + kk*32);
        #pragma unroll
        for (int nt = 0; nt < 4; ++nt)
            #pragma unroll
            for (int mt = 0; mt < 4; ++mt)
                acc[nt][mt] = __builtin_amdgcn_mfma_f32_16x16x32_bf16(
                    bfr[nt], af[mt], acc[nt][mt], 0, 0, 0);
    }

    // ---- O writes: col(l15) -> (i,c); row(quad,r) -> (j,d) ----
    #pragma unroll
    for (int mt = 0; mt < 4; ++mt) {
        const int Mcol = mq*64 + mt*16 + l15;
        const int i_l = Mcol >> 5, c = Mcol & 31;
        #pragma unroll
        for (int nt = 0; nt < 4; ++nt) {
            const int Nrow = nq*64 + nt*16 + quad*4;
            const int j_l = Nrow >> 5, d0 = Nrow & 31;
            const int p = i_l*8 + j_l;
            pack4 pk;
            #pragma unroll
            for (int r = 0; r < 4; ++r) pk.h[r] = __float2bfloat16(acc[nt][mt][r]);
            *(uint2*)&O[p*OR + c*36 + d0] = pk.u;
        }
    }
    __syncthreads();

    // ---- stage 3: wave = (16-z slice zs, 32-p half ph); wf in 4x8 chunks ----
    const int zs = wave >> 1, ph = wave & 1;
    const int zb = zs * 16;
    f32x4 oacc[2];
    oacc[0] = z4; oacc[1] = z4;

    #pragma unroll
    for (int h = 0; h < 4; ++h) {
        bf16x8 wf[8];
        #pragma unroll
        for (int k2 = 0; k2 < 8; ++k2)
            wf[k2] = *(const bf16x8*)&woutT[(size_t)(zb + l15) * (CH*CH)
                                            + (h*8 + k2)*32 + quad*8];
        #pragma unroll
        for (int k2 = 0; k2 < 8; ++k2) {
            const int kk = h*8 + k2;
            #pragma unroll
            for (int mt2 = 0; mt2 < 2; ++mt2) {
                bf16x8 a = *(const bf16x8*)&O[(ph*32 + mt2*16 + l15)*OR
                                              + kk*36 + quad*8];
                oacc[mt2] = __builtin_amdgcn_mfma_f32_16x16x32_bf16(
                    a, wf[k2], oacc[mt2], 0, 0, 0);
            }
        }
    }

    // ---- epilogue: col(l15) -> z, row(quad,r) -> p ----
    const int zc = zb + l15;
    const float bz = bout[zc];
    #pragma unroll
    for (int mt2 = 0; mt2 < 2; ++mt2) {
        #pragma unroll
        for (int r = 0; r < 4; ++r) {
            const int p = ph*32 + mt2*16 + quad*4 + r;
            const int i = i0 + (p >> 3), j = j0 + (p & 7);
            const float rn = RN[i*N_ + j];
            out[((size_t)(i*N_ + j))*CZ + zc] = (oacc[mt2][r] + bz) * rn;
        }
    }
}

extern "C" void kernel_launch(void* const* d_in, const int* in_sizes, int n_in,
                              void* d_out, int out_size, void* d_ws, size_t ws_size,
                              hipStream_t stream)
{
    const float* m    = (const float*)d_in[0];
    const float* mask = (const float*)d_in[1];
    const float* gam  = (const float*)d_in[2];
    const float* bet  = (const float*)d_in[3];
    const float* w1   = (const float*)d_in[4];
    const float* b1   = (const float*)d_in[5];
    const float* w2   = (const float*)d_in[6];
    const float* b2   = (const float*)d_in[7];
    const float* wout = (const float*)d_in[8];
    const float* bout = (const float*)d_in[9];
    float* out = (float*)d_out;

    __hip_bfloat16* At    = (__hip_bfloat16*)d_ws;                 // [N][CH][S]
    __hip_bfloat16* Bt    = At + (size_t)N_ * CH * S_;             // [N][CH][S]
    __hip_bfloat16* woutT = Bt + (size_t)N_ * CH * S_;             // [CZ][1024]
    __hip_bfloat16* wt12  = woutT + (size_t)CZ * CH * CH;          // [64][256]
    float*          RN    = (float*)(wt12 + (size_t)64 * CM);      // [N][N]

    k_prep<<<576, 384, 0, stream>>>(w1, w2, wout, mask, wt12, woutT, RN);
    dim3 gl(24, 16);
    k_lnp<<<gl, 256, 0, stream>>>(m, mask, gam, bet, b1, b2, wt12, At, Bt);
    dim3 grid(N_ / 8, N_ / 8);
    k_opm<<<grid, 1024, 0, stream>>>(At, Bt, RN, woutT, bout, out);
}

// Round 11
// 312.092 us; speedup vs baseline: 1.3327x; 1.3327x over previous
//
#include <hip/hip_runtime.h>
#include <hip/hip_bf16.h>

#define S_ 128
#define N_ 384
#define CM 256
#define CH 32
#define CZ 128

typedef __attribute__((ext_vector_type(8))) __bf16 bf16x8;
typedef __attribute__((ext_vector_type(4))) float f32x4;

union pack4 { __hip_bfloat16 h[4]; uint2 u; };

// ---- Kernel P: fused prep (wt12 + woutT + RN) — one launch ---------------
// blocks 0..63    : wt12[64][256] bf16 = [w1|w2]^T     (t < 256 active)
// blocks 64..191  : woutT[z][cd] bf16
// blocks 192..575 : RN[i][j] = 1/(mask^T mask + eps)   (384 thr = j)
__global__ __launch_bounds__(384) void k_prep(const float* __restrict__ w1,
                                              const float* __restrict__ w2,
                                              const float* __restrict__ wout,
                                              const float* __restrict__ mask,
                                              __hip_bfloat16* __restrict__ wt12,
                                              __hip_bfloat16* __restrict__ woutT,
                                              float* __restrict__ RN)
{
    const int b = blockIdx.x, t = threadIdx.x;
    if (b < 64) {
        if (t < 256) {
            const float* w = (b < CH) ? w1 : w2;
            wt12[b * CM + t] = __float2bfloat16(w[(size_t)t * CH + (b & 31)]);
        }
    } else if (b < 192) {
        const int z = b - 64;
        for (int cd = t; cd < CH*CH; cd += 384)
            woutT[(size_t)z * (CH*CH) + cd] = __float2bfloat16(wout[(size_t)cd * CZ + z]);
    } else {
        const int i = b - 192, j = t;
        float acc = 0.f;
        #pragma unroll 8
        for (int s = 0; s < S_; ++s)
            acc += mask[s*N_ + i] * mask[s*N_ + j];
        RN[i*N_ + j] = 1.0f / (acc + 1e-3f);
    }
}

// ---- Kernel 1: LayerNorm + dual projection via MFMA ----------------------
// LN phase REWORKED (the un-profiled ~127 us non-opm time lives here):
// old: each wave did 32 SERIAL rows, each with a 6-level 64-lane shfl_xor
// chain whose off=32/16 hops are LDS-routed cross-half permutes (~30 cy,
// serialized). new: each row owned by a 16-LANE GROUP (4 rows/wave in
// flight): 4x float4 per lane, reduction = 4 shfl_xor levels (off 8..1,
// intra-16-lane, DPP-fast), 8 group-iterations. Loads stay coalesced
// (16 lanes x consecutive float4 = 256 B); lnS layout and everything
// downstream (MFMA stage, At/Bt stores) byte-identical to the champion.
#define LNR 264
__global__ __launch_bounds__(256) void k_lnp(
    const float* __restrict__ m, const float* __restrict__ mask,
    const float* __restrict__ gamma, const float* __restrict__ beta,
    const float* __restrict__ b1, const float* __restrict__ b2,
    const __hip_bfloat16* __restrict__ wt12,
    __hip_bfloat16* __restrict__ At, __hip_bfloat16* __restrict__ Bt)
{
    __shared__ __hip_bfloat16 lnS[128 * LNR];
    __shared__ float msk[128];
    const int n0 = blockIdx.x * 16, s0 = blockIdx.y * 8;
    const int t = threadIdx.x, wave = t >> 6, lane = t & 63;
    const int l15 = lane & 15, quad = lane >> 4;

    if (t < 128) msk[t] = mask[(s0 + (t & 7))*N_ + n0 + (t >> 3)];

    // gamma/beta slices for this lane's 16 columns (u*16+l15)*4 .. +3
    float4 ga[4], be4[4];
    #pragma unroll
    for (int u = 0; u < 4; ++u) {
        ga[u]  = ((const float4*)gamma)[u*16 + l15];
        be4[u] = ((const float4*)beta )[u*16 + l15];
    }

    // 8 iterations of 4 rows (g = lane>>4 selects row within group)
    for (int it = 0; it < 8; ++it) {
        const int row = wave*32 + it*4 + quad;
        const int n = row >> 3, s = row & 7;
        const float4* src = (const float4*)(m + ((size_t)((s0+s)*N_ + n0 + n)) * CM);
        float4 x[4];
        #pragma unroll
        for (int u = 0; u < 4; ++u) x[u] = src[u*16 + l15];

        float sum = 0.f, ssq = 0.f;
        #pragma unroll
        for (int u = 0; u < 4; ++u) {
            sum += x[u].x + x[u].y + x[u].z + x[u].w;
            ssq += x[u].x*x[u].x + x[u].y*x[u].y + x[u].z*x[u].z + x[u].w*x[u].w;
        }
        #pragma unroll
        for (int off = 8; off >= 1; off >>= 1) {   // intra-16-lane butterfly
            sum += __shfl_xor(sum, off, 64);
            ssq += __shfl_xor(ssq, off, 64);
        }
        const float mean = sum * (1.0f/CM);
        const float var  = ssq * (1.0f/CM) - mean*mean;
        const float rstd = rsqrtf(var + 1e-5f);

        #pragma unroll
        for (int u = 0; u < 4; ++u) {
            pack4 pk;
            pk.h[0] = __float2bfloat16((x[u].x - mean)*rstd*ga[u].x + be4[u].x);
            pk.h[1] = __float2bfloat16((x[u].y - mean)*rstd*ga[u].y + be4[u].y);
            pk.h[2] = __float2bfloat16((x[u].z - mean)*rstd*ga[u].z + be4[u].z);
            pk.h[3] = __float2bfloat16((x[u].w - mean)*rstd*ga[u].w + be4[u].w);
            *(uint2*)&lnS[row*LNR + (u*16 + l15)*4] = pk.u;
        }
    }
    __syncthreads();

    f32x4 acc[2][4];
    const f32x4 z4 = {0.f,0.f,0.f,0.f};
    #pragma unroll
    for (int mt = 0; mt < 2; ++mt)
        #pragma unroll
        for (int nt = 0; nt < 4; ++nt) acc[mt][nt] = z4;

    #pragma unroll
    for (int kk = 0; kk < 8; ++kk) {
        bf16x8 a0 = *(const bf16x8*)&lnS[(wave*32      + l15)*LNR + kk*32 + quad*8];
        bf16x8 a1 = *(const bf16x8*)&lnS[(wave*32 + 16 + l15)*LNR + kk*32 + quad*8];
        #pragma unroll
        for (int nt = 0; nt < 4; ++nt) {
            bf16x8 wv = *(const bf16x8*)&wt12[(size_t)(nt*16 + l15)*CM + kk*32 + quad*8];
            acc[0][nt] = __builtin_amdgcn_mfma_f32_16x16x32_bf16(a0, wv, acc[0][nt], 0,0,0);
            acc[1][nt] = __builtin_amdgcn_mfma_f32_16x16x32_bf16(a1, wv, acc[1][nt], 0,0,0);
        }
    }

    #pragma unroll
    for (int nt = 0; nt < 4; ++nt) {
        const int ncol = nt*16 + l15;
        const int sel = ncol >> 5, c = ncol & 31;
        const float bias = sel ? b2[c] : b1[c];
        __hip_bfloat16* dst = sel ? Bt : At;
        #pragma unroll
        for (int mt = 0; mt < 2; ++mt) {
            const int rowb = wave*32 + mt*16 + quad*4;
            const int n_loc = rowb >> 3, s_loc = rowb & 7;
            pack4 pk;
            #pragma unroll
            for (int r = 0; r < 4; ++r)
                pk.h[r] = __float2bfloat16((acc[mt][nt][r] + bias) * msk[rowb + r]);
            *(uint2*)&dst[((size_t)(n0 + n_loc)*CH + c)*S_ + s0 + s_loc] = pk.u;
        }
    }
}

// ---- Kernel 2: fused MFMA outer-product + w_out GEMM (R7 champion) -------
// EXACT R7 kernel (196 us, spill-free, VGPR 124). R8/R9/R10 proved
// 4 waves/SIMD is unreachable for this shape (128-total cap forces spill
// three different ways) -> this 512-thr / 2-waves-per-SIMD version is the
// keeper. wf loaded AFTER the barrier in two 16-frag chunks.
#define OR 1160
__global__ __launch_bounds__(512) void k_opm(
    const __hip_bfloat16* __restrict__ At, const __hip_bfloat16* __restrict__ Bt,
    const float* __restrict__ RN, const __hip_bfloat16* __restrict__ woutT,
    const float* __restrict__ bout, float* __restrict__ out)
{
    __shared__ __hip_bfloat16 O[64 * OR];   // 145 KB
    const int t = threadIdx.x;
    const int wave = t >> 6, lane = t & 63;
    const int l15 = lane & 15, quad = lane >> 4;
    const int i0 = blockIdx.x * 8, j0 = blockIdx.y * 8;
    const int mhalf = wave & 1, nquad = wave >> 1;

    // ---- stage 2: acc[nt][mt] = D[(j,d)][(i,c)] ----
    f32x4 acc[4][8];
    const f32x4 z4 = {0.f,0.f,0.f,0.f};
    #pragma unroll
    for (int nt = 0; nt < 4; ++nt)
        #pragma unroll
        for (int mt = 0; mt < 8; ++mt) acc[nt][mt] = z4;

    const __hip_bfloat16* Ag[8];
    #pragma unroll
    for (int mt = 0; mt < 8; ++mt) {
        const int Mrow = mhalf*128 + mt*16 + l15;     // = i_l*32 + c
        Ag[mt] = At + ((size_t)(i0 + (Mrow >> 5)) * CH + (Mrow & 31)) * S_ + quad*8;
    }
    const __hip_bfloat16* Bg[4];
    #pragma unroll
    for (int nt = 0; nt < 4; ++nt) {
        const int Ncol = nquad*64 + nt*16 + l15;      // = j_l*32 + d
        Bg[nt] = Bt + ((size_t)(j0 + (Ncol >> 5)) * CH + (Ncol & 31)) * S_ + quad*8;
    }

    #pragma unroll
    for (int kk = 0; kk < 4; ++kk) {
        bf16x8 af[8], bfr[4];
        #pragma unroll
        for (int mt = 0; mt < 8; ++mt) af[mt] = *(const bf16x8*)(Ag[mt] + kk*32);
        #pragma unroll
        for (int nt = 0; nt < 4; ++nt) bfr[nt] = *(const bf16x8*)(Bg[nt] + kk*32);
        #pragma unroll
        for (int nt = 0; nt < 4; ++nt)
            #pragma unroll
            for (int mt = 0; mt < 8; ++mt)
                acc[nt][mt] = __builtin_amdgcn_mfma_f32_16x16x32_bf16(
                    bfr[nt], af[mt], acc[nt][mt], 0, 0, 0);
    }

    // ---- O writes: col(l15) -> (i,c); row(quad,r) -> (j,d), r = consec d ----
    #pragma unroll
    for (int mt = 0; mt < 8; ++mt) {
        const int Mcol = mhalf*128 + mt*16 + l15;
        const int i_l = Mcol >> 5, c = Mcol & 31;
        #pragma unroll
        for (int nt = 0; nt < 4; ++nt) {
            const int Nrow = nquad*64 + nt*16 + quad*4;
            const int j_l = Nrow >> 5, d0 = Nrow & 31;
            const int p = i_l*8 + j_l;
            pack4 pk;
            #pragma unroll
            for (int r = 0; r < 4; ++r) pk.h[r] = __float2bfloat16(acc[nt][mt][r]);
            *(uint2*)&O[p*OR + c*36 + d0] = pk.u;
        }
    }
    __syncthreads();

    // ---- stage 3: wave's exclusive 16-z slice; wf loaded post-barrier,
    //      two 16-frag chunks, oacc carried across chunks ----
    const int zb = wave * 16;
    f32x4 oacc[4];
    #pragma unroll
    for (int mt = 0; mt < 4; ++mt) oacc[mt] = z4;

    #pragma unroll
    for (int h = 0; h < 2; ++h) {
        bf16x8 wf[16];
        #pragma unroll
        for (int k2 = 0; k2 < 16; ++k2)
            wf[k2] = *(const bf16x8*)&woutT[(size_t)(zb + l15) * (CH*CH)
                                            + (h*16 + k2)*32 + quad*8];
        #pragma unroll
        for (int k2 = 0; k2 < 16; ++k2) {
            const int kk = h*16 + k2;
            #pragma unroll
            for (int mt = 0; mt < 4; ++mt) {
                bf16x8 a = *(const bf16x8*)&O[(mt*16 + l15)*OR + kk*36 + quad*8];
                oacc[mt] = __builtin_amdgcn_mfma_f32_16x16x32_bf16(
                    a, wf[k2], oacc[mt], 0, 0, 0);
            }
        }
    }

    // ---- epilogue: col(l15) -> z, row(quad,r) -> p ----
    const int zc = zb + l15;
    const float bz = bout[zc];
    #pragma unroll
    for (int mt = 0; mt < 4; ++mt) {
        #pragma unroll
        for (int r = 0; r < 4; ++r) {
            const int p = mt*16 + quad*4 + r;
            const int i = i0 + (p >> 3), j = j0 + (p & 7);
            const float rn = RN[i*N_ + j];
            out[((size_t)(i*N_ + j))*CZ + zc] = (oacc[mt][r] + bz) * rn;
        }
    }
}

extern "C" void kernel_launch(void* const* d_in, const int* in_sizes, int n_in,
                              void* d_out, int out_size, void* d_ws, size_t ws_size,
                              hipStream_t stream)
{
    const float* m    = (const float*)d_in[0];
    const float* mask = (const float*)d_in[1];
    const float* gam  = (const float*)d_in[2];
    const float* bet  = (const float*)d_in[3];
    const float* w1   = (const float*)d_in[4];
    const float* b1   = (const float*)d_in[5];
    const float* w2   = (const float*)d_in[6];
    const float* b2   = (const float*)d_in[7];
    const float* wout = (const float*)d_in[8];
    const float* bout = (const float*)d_in[9];
    float* out = (float*)d_out;

    __hip_bfloat16* At    = (__hip_bfloat16*)d_ws;                 // [N][CH][S]
    __hip_bfloat16* Bt    = At + (size_t)N_ * CH * S_;             // [N][CH][S]
    __hip_bfloat16* woutT = Bt + (size_t)N_ * CH * S_;             // [CZ][1024]
    __hip_bfloat16* wt12  = woutT + (size_t)CZ * CH * CH;          // [64][256]
    float*          RN    = (float*)(wt12 + (size_t)64 * CM);      // [N][N]

    k_prep<<<576, 384, 0, stream>>>(w1, w2, wout, mask, wt12, woutT, RN);
    dim3 gl(24, 16);
    k_lnp<<<gl, 256, 0, stream>>>(m, mask, gam, bet, b1, b2, wt12, At, Bt);
    dim3 grid(N_ / 8, N_ / 8);
    k_opm<<<grid, 512, 0, stream>>>(At, Bt, RN, woutT, bout, out);
}